// Round 9
// baseline (818.570 us; speedup 1.0000x reference)
//
#include <hip/hip_runtime.h>

#define DFEAT 64

typedef __attribute__((ext_vector_type(8))) short bf16x8;
typedef __attribute__((ext_vector_type(4))) float f32x4;

// ---------------- bf16 helpers (OCP bfloat16, RNE pack) ----------------
__device__ __forceinline__ float bfhi(unsigned int u) {
    return __builtin_bit_cast(float, u & 0xFFFF0000u);
}
__device__ __forceinline__ float bflo(unsigned int u) {
    return __builtin_bit_cast(float, u << 16);
}
__device__ __forceinline__ unsigned short f2bf(float f) { // RNE
    unsigned int u = __builtin_bit_cast(unsigned int, f);
    u += 0x7FFFu + ((u >> 16) & 1u);
    return (unsigned short)(u >> 16);
}
__device__ __forceinline__ float4 upk4(uint2 v) {
    float4 r;
    r.x = bflo(v.x); r.y = bfhi(v.x);
    r.z = bflo(v.y); r.w = bfhi(v.y);
    return r;
}

// ============================================================================
// fp32 -> bf16 conversion (features once; 6 weight matrices once)
// ============================================================================
__global__ void __launch_bounds__(256)
cvt_bf16_kernel(const float* __restrict__ in, unsigned short* __restrict__ outb,
                int n4) {
    int i = blockIdx.x * 256 + threadIdx.x;
    if (i >= n4) return;
    const float4 v = reinterpret_cast<const float4*>(in)[i];
    uint2 p;
    p.x = (unsigned int)f2bf(v.x) | ((unsigned int)f2bf(v.y) << 16);
    p.y = (unsigned int)f2bf(v.z) | ((unsigned int)f2bf(v.w) << 16);
    reinterpret_cast<uint2*>(outb)[i] = p;
}

// ============================================================================
// CSR build (once per call; edge_index shared by all 3 layers)
// ============================================================================
__global__ void __launch_bounds__(256)
deg_count_kernel(const int* __restrict__ dsts, int* __restrict__ degi, int E) {
    int e = blockIdx.x * 256 + threadIdx.x;
    if (e < E) atomicAdd(&degi[dsts[e]], 1);
}

__global__ void __launch_bounds__(1024)
block_sum_kernel(const int* __restrict__ degi, int* __restrict__ bsum, int N) {
    __shared__ int sm[1024];
    int idx = blockIdx.x * 1024 + threadIdx.x;
    sm[threadIdx.x] = (idx < N) ? degi[idx] : 0;
    __syncthreads();
    for (int s = 512; s > 0; s >>= 1) {
        if (threadIdx.x < s) sm[threadIdx.x] += sm[threadIdx.x + s];
        __syncthreads();
    }
    if (threadIdx.x == 0) bsum[blockIdx.x] = sm[0];
}

__global__ void __launch_bounds__(64)
scan_bsum_kernel(int* __restrict__ bsum, int nb) {
    if (threadIdx.x == 0 && blockIdx.x == 0) {
        int run = 0;
        for (int i = 0; i < nb; ++i) { int v = bsum[i]; bsum[i] = run; run += v; }
    }
}

__global__ void __launch_bounds__(1024)
scan_final_kernel(const int* __restrict__ degi, const int* __restrict__ bsum,
                  int* __restrict__ rowptr, int* __restrict__ cursor, int N) {
    __shared__ int sm[1024];
    int idx = blockIdx.x * 1024 + threadIdx.x;
    int v = (idx < N) ? degi[idx] : 0;
    sm[threadIdx.x] = v;
    __syncthreads();
    for (int s = 1; s < 1024; s <<= 1) {
        int t = (threadIdx.x >= s) ? sm[threadIdx.x - s] : 0;
        __syncthreads();
        sm[threadIdx.x] += t;
        __syncthreads();
    }
    int excl = bsum[blockIdx.x] + sm[threadIdx.x] - v;
    if (idx < N) { rowptr[idx] = excl; cursor[idx] = excl; }
    if (idx == N - 1) rowptr[N] = excl + v;
}

// Partitioned fill (R6-verified win): pass p handles dst in [lo,hi) only ->
// active col slice ~800 KB -> L2 write-combines.
__global__ void __launch_bounds__(256)
fill_pass_kernel(const int* __restrict__ srcs, const int* __restrict__ dsts,
                 int* __restrict__ cursor, int* __restrict__ col, int E,
                 int lo, int hi) {
    int e = blockIdx.x * 256 + threadIdx.x;
    if (e < E) {
        int d = dsts[e];
        if (d >= lo && d < hi) {
            int pos = atomicAdd(&cursor[d], 1);
            col[pos] = srcs[e];
        }
    }
}

// ============================================================================
// Gather-mean over bf16 rows (128 B). One wave per node, NO LDS, NO barriers
// (R4-verified: free-running waves beat fused/barriered variants).
// ============================================================================
__global__ void __launch_bounds__(256)
gather_mean_kernel(const unsigned short* __restrict__ xb,
                   const int* __restrict__ rowptr, const int* __restrict__ col,
                   unsigned short* __restrict__ meanb, int N) {
    int w = (blockIdx.x * 256 + threadIdx.x) >> 6;
    if (w >= N) return;
    const int lane = threadIdx.x & 63;
    const int r = lane >> 4;
    const int c = lane & 15;
    const uint2* x2 = reinterpret_cast<const uint2*>(xb);
    uint2* mean2 = reinterpret_cast<uint2*>(meanb);

    int st = rowptr[w], en = rowptr[w + 1];
    int deg = en - st;

    if (deg == 0) {
        if (r == 0) mean2[(size_t)w * 16 + c] = make_uint2(0, 0);
        return;
    }

    int nb = col[st + min(lane, deg - 1)];
    float4 acc = make_float4(0, 0, 0, 0);

#pragma unroll
    for (int k = 0; k < 4; ++k) {            // slots 0..15 (always)
        int i = 4 * k + r;
        int q = __shfl(nb, min(i, deg - 1), 64);
        float4 v = upk4(x2[(size_t)q * 16 + c]);
        float m = (i < deg) ? 1.0f : 0.0f;
        acc.x += v.x * m; acc.y += v.y * m; acc.z += v.z * m; acc.w += v.w * m;
    }
    if (deg > 16) {
#pragma unroll
        for (int k = 4; k < 8; ++k) {
            int i = 4 * k + r;
            int q = __shfl(nb, min(i, deg - 1), 64);
            float4 v = upk4(x2[(size_t)q * 16 + c]);
            float m = (i < deg) ? 1.0f : 0.0f;
            acc.x += v.x * m; acc.y += v.y * m; acc.z += v.z * m; acc.w += v.w * m;
        }
    }
    if (deg > 32) {
#pragma unroll
        for (int k = 8; k < 16; ++k) {
            int i = 4 * k + r;
            int q = __shfl(nb, min(i, deg - 1), 64);
            float4 v = upk4(x2[(size_t)q * 16 + c]);
            float m = (i < deg) ? 1.0f : 0.0f;
            acc.x += v.x * m; acc.y += v.y * m; acc.z += v.z * m; acc.w += v.w * m;
        }
    }
    for (int base = 64; base < deg; base += 64) {
        int cnt = deg - base;
        int nb2 = col[st + base + min(lane, cnt - 1)];
#pragma unroll
        for (int k = 0; k < 16; ++k) {
            int i = 4 * k + r;
            int q = __shfl(nb2, min(i, cnt - 1), 64);
            float4 v = upk4(x2[(size_t)q * 16 + c]);
            float m = (i < cnt) ? 1.0f : 0.0f;
            acc.x += v.x * m; acc.y += v.y * m; acc.z += v.z * m; acc.w += v.w * m;
        }
    }

#pragma unroll
    for (int off = 16; off <= 32; off <<= 1) {
        acc.x += __shfl_xor(acc.x, off, 64);
        acc.y += __shfl_xor(acc.y, off, 64);
        acc.z += __shfl_xor(acc.z, off, 64);
        acc.w += __shfl_xor(acc.w, off, 64);
    }
    float inv = 1.0f / (float)deg;
    if (r == 0) {
        uint2 p;
        p.x = (unsigned int)f2bf(acc.x * inv) | ((unsigned int)f2bf(acc.y * inv) << 16);
        p.y = (unsigned int)f2bf(acc.z * inv) | ((unsigned int)f2bf(acc.w * inv) << 16);
        mean2[(size_t)w * 16 + c] = p;
    }
}

// ============================================================================
// MFMA transform v2: D[node][:] = [mean|x] @ [Wl|Wr]^T (K=128) + bl; L2norm;
// ReLU. One wave per 16-node tile; B (weights) + A from global (weights are
// 16 KB -> L1-resident). Epilogue: repack through per-wave LDS tile, then
// store full 128 B rows as coalesced dwordx2 (NO sub-dword global stores --
// R8's 3.4x write-amplification / serialization bug).
//   A frag s: A[m=lane&15][k=quad*8+j]; s=0,1 mean halves, s=2,3 x halves
//   B frag [t][s]: W[16t+(lane&15)][k]
//   C/D: col(n)=lane&15, row(m)=quad*4+reg
// ============================================================================
__global__ void __launch_bounds__(256)
transform_mfma_kernel(const unsigned short* __restrict__ xb,
                      const unsigned short* __restrict__ meanb,
                      const unsigned short* __restrict__ Wlb,
                      const float* __restrict__ bl,
                      const unsigned short* __restrict__ Wrb,
                      unsigned short* __restrict__ h_out,
                      const int* __restrict__ batch, float* __restrict__ out,
                      int N, int final_layer) {
    constexpr int RS = DFEAT + 4;            // 68-ushort repack row stride
    __shared__ unsigned short rep[4][16 * RS];  // per-wave 16-node output tile

    const int wib  = threadIdx.x >> 6;
    const int lane = threadIdx.x & 63;
    const int colx = lane & 15;
    const int quad = lane >> 4;
    unsigned short* rp = rep[wib];

    // resident B fragments: 4 out-tiles x 4 k-steps (L1-served, ~80 VGPRs)
    bf16x8 Bf[4][4];
    float  bias[4];
#pragma unroll
    for (int t = 0; t < 4; ++t) {
        const unsigned short* wl = Wlb + (size_t)(16 * t + colx) * 64 + quad * 8;
        const unsigned short* wr = Wrb + (size_t)(16 * t + colx) * 64 + quad * 8;
        Bf[t][0] = *reinterpret_cast<const bf16x8*>(wl);
        Bf[t][1] = *reinterpret_cast<const bf16x8*>(wl + 32);
        Bf[t][2] = *reinterpret_cast<const bf16x8*>(wr);
        Bf[t][3] = *reinterpret_cast<const bf16x8*>(wr + 32);
        bias[t] = bl[16 * t + colx];
    }

    const int tiles = (N + 15) >> 4;
    const int nwaves = gridDim.x * 4;
    int wid = (blockIdx.x * 256 + threadIdx.x) >> 6;

    for (int tile = wid; tile < tiles; tile += nwaves) {
        int m = tile * 16 + colx;
        int mc = min(m, N - 1);
        const unsigned short* mrow = meanb + (size_t)mc * 64 + quad * 8;
        const unsigned short* xrow = xb    + (size_t)mc * 64 + quad * 8;
        bf16x8 A0 = *reinterpret_cast<const bf16x8*>(mrow);
        bf16x8 A1 = *reinterpret_cast<const bf16x8*>(mrow + 32);
        bf16x8 A2 = *reinterpret_cast<const bf16x8*>(xrow);
        bf16x8 A3 = *reinterpret_cast<const bf16x8*>(xrow + 32);

        f32x4 acc[4];
#pragma unroll
        for (int t = 0; t < 4; ++t) {
            f32x4 a = {0.0f, 0.0f, 0.0f, 0.0f};
            a = __builtin_amdgcn_mfma_f32_16x16x32_bf16(A0, Bf[t][0], a, 0, 0, 0);
            a = __builtin_amdgcn_mfma_f32_16x16x32_bf16(A1, Bf[t][1], a, 0, 0, 0);
            a = __builtin_amdgcn_mfma_f32_16x16x32_bf16(A2, Bf[t][2], a, 0, 0, 0);
            a = __builtin_amdgcn_mfma_f32_16x16x32_bf16(A3, Bf[t][3], a, 0, 0, 0);
            acc[t] = a;
        }

        // epilogue: +bias, per-node L2 norm, ReLU, repack to LDS (bank-clean)
#pragma unroll
        for (int r = 0; r < 4; ++r) {
            float o0 = acc[0][r] + bias[0];
            float o1 = acc[1][r] + bias[1];
            float o2 = acc[2][r] + bias[2];
            float o3 = acc[3][r] + bias[3];
            float ss = o0 * o0 + o1 * o1 + o2 * o2 + o3 * o3;
            ss += __shfl_xor(ss, 1, 64);   // shfl over colx bits: same node
            ss += __shfl_xor(ss, 2, 64);
            ss += __shfl_xor(ss, 4, 64);
            ss += __shfl_xor(ss, 8, 64);
            float inv = 1.0f / fmaxf(sqrtf(ss), 1e-12f);
            o0 = fmaxf(o0 * inv, 0.0f);
            o1 = fmaxf(o1 * inv, 0.0f);
            o2 = fmaxf(o2 * inv, 0.0f);
            o3 = fmaxf(o3 * inv, 0.0f);

            int nl = quad * 4 + r;           // local node 0..15
            if (final_layer) {
                int node = tile * 16 + nl;
                if (node < N) {
                    float* orow = out + (size_t)batch[node] * DFEAT + colx;
                    atomicAdd(orow,      o0);
                    atomicAdd(orow + 16, o1);
                    atomicAdd(orow + 32, o2);
                    atomicAdd(orow + 48, o3);
                }
            } else {
                unsigned short* rrow = rp + nl * RS;
                rrow[colx]      = f2bf(o0);
                rrow[colx + 16] = f2bf(o1);
                rrow[colx + 32] = f2bf(o2);
                rrow[colx + 48] = f2bf(o3);
            }
        }

        if (!final_layer) {
            // same-wave LDS readback (lgkmcnt ordered) -> coalesced row stores
#pragma unroll
            for (int i = 0; i < 4; ++i) {
                int nl2 = 4 * i + quad;
                int node = tile * 16 + nl2;
                if (node < N) {
                    uint2 v = *reinterpret_cast<const uint2*>(&rp[nl2 * RS + colx * 4]);
                    *reinterpret_cast<uint2*>(h_out + (size_t)node * 64 + colx * 4) = v;
                }
            }
        }
    }
}

// ============================================================================
extern "C" void kernel_launch(void* const* d_in, const int* in_sizes, int n_in,
                              void* d_out, int out_size, void* d_ws, size_t ws_size,
                              hipStream_t stream) {
    const float* x_raw = (const float*)d_in[0];
    const int*   eidx  = (const int*)d_in[1];
    const int*   batch = (const int*)d_in[2];
    const float* Wl0 = (const float*)d_in[3];
    const float* bl0 = (const float*)d_in[4];
    const float* Wr0 = (const float*)d_in[5];
    const float* Wl1 = (const float*)d_in[6];
    const float* bl1 = (const float*)d_in[7];
    const float* Wr1 = (const float*)d_in[8];
    const float* Wl2 = (const float*)d_in[9];
    const float* bl2 = (const float*)d_in[10];
    const float* Wr2 = (const float*)d_in[11];

    const int N = in_sizes[0] / DFEAT;
    const int E = in_sizes[1] / 2;
    const int* srcs = eidx;
    const int* dsts = eidx + E;
    float* out = (float*)d_out;

    const int nb = (N + 1023) / 1024;

    char* ws = (char*)d_ws;
    auto align512 = [](size_t v) { return (v + 511) & ~(size_t)511; };
    size_t off = 0;
    int* degi   = (int*)(ws + off); off += align512((size_t)N * 4);
    int* rowptr = (int*)(ws + off); off += align512(((size_t)N + 1) * 4);
    int* cursor = (int*)(ws + off); off += align512((size_t)N * 4);
    int* bsum   = (int*)(ws + off); off += align512((size_t)nb * 4);
    int* col    = (int*)(ws + off); off += align512((size_t)E * 4);
    unsigned short* xb    = (unsigned short*)(ws + off); off += align512((size_t)N * DFEAT * 2);
    unsigned short* meanb = (unsigned short*)(ws + off); off += align512((size_t)N * DFEAT * 2);
    unsigned short* hA    = (unsigned short*)(ws + off); off += align512((size_t)N * DFEAT * 2);
    unsigned short* hB    = (unsigned short*)(ws + off); off += align512((size_t)N * DFEAT * 2);
    unsigned short* wb[6];
    for (int i = 0; i < 6; ++i) {
        wb[i] = (unsigned short*)(ws + off);
        off += align512((size_t)DFEAT * DFEAT * 2);
    }

    hipMemsetAsync(degi, 0, (size_t)N * 4, stream);
    hipMemsetAsync(out, 0, (size_t)out_size * 4, stream);

    // bf16 conversions: features + 6 weight matrices
    const int n4 = N * DFEAT / 4;
    cvt_bf16_kernel<<<(n4 + 255) / 256, 256, 0, stream>>>(x_raw, xb, n4);
    const int w4 = DFEAT * DFEAT / 4;
    const float* wsrc[6] = {Wl0, Wr0, Wl1, Wr1, Wl2, Wr2};
    for (int i = 0; i < 6; ++i)
        cvt_bf16_kernel<<<(w4 + 255) / 256, 256, 0, stream>>>(wsrc[i], wb[i], w4);

    // CSR build
    deg_count_kernel<<<(E + 255) / 256, 256, 0, stream>>>(dsts, degi, E);
    block_sum_kernel<<<nb, 1024, 0, stream>>>(degi, bsum, N);
    scan_bsum_kernel<<<1, 64, 0, stream>>>(bsum, nb);
    scan_final_kernel<<<nb, 1024, 0, stream>>>(degi, bsum, rowptr, cursor, N);
    const int NPASS = 8;
    const int rng = (N + NPASS - 1) / NPASS;
    for (int p = 0; p < NPASS; ++p) {
        int lo = p * rng;
        int hi = min(N, lo + rng);
        fill_pass_kernel<<<(E + 255) / 256, 256, 0, stream>>>(srcs, dsts, cursor,
                                                              col, E, lo, hi);
    }

    const int gatherBlocks = (N + 3) / 4;   // one wave per node
    const int xfBlocks     = 2048;          // wave per 16-node tile

    // ---- layer 0
    gather_mean_kernel<<<gatherBlocks, 256, 0, stream>>>(xb, rowptr, col, meanb, N);
    transform_mfma_kernel<<<xfBlocks, 256, 0, stream>>>(xb, meanb, wb[0], bl0, wb[1],
                                                        hA, nullptr, nullptr, N, 0);
    // ---- layer 1
    gather_mean_kernel<<<gatherBlocks, 256, 0, stream>>>(hA, rowptr, col, meanb, N);
    transform_mfma_kernel<<<xfBlocks, 256, 0, stream>>>(hA, meanb, wb[2], bl1, wb[3],
                                                        hB, nullptr, nullptr, N, 0);
    // ---- layer 2
    gather_mean_kernel<<<gatherBlocks, 256, 0, stream>>>(hB, rowptr, col, meanb, N);
    transform_mfma_kernel<<<xfBlocks, 256, 0, stream>>>(hB, meanb, wb[4], bl2, wb[5],
                                                        nullptr, batch, out, N, 1);
}

// Round 10
// 743.423 us; speedup vs baseline: 1.1011x; 1.1011x over previous
//
#include <hip/hip_runtime.h>

#define DFEAT 64

typedef __attribute__((ext_vector_type(8))) short bf16x8;
typedef __attribute__((ext_vector_type(4))) float f32x4;

// ---------------- bf16 helpers (OCP bfloat16, RNE pack) ----------------
__device__ __forceinline__ float bfhi(unsigned int u) {
    return __builtin_bit_cast(float, u & 0xFFFF0000u);
}
__device__ __forceinline__ float bflo(unsigned int u) {
    return __builtin_bit_cast(float, u << 16);
}
__device__ __forceinline__ unsigned short f2bf(float f) { // RNE
    unsigned int u = __builtin_bit_cast(unsigned int, f);
    u += 0x7FFFu + ((u >> 16) & 1u);
    return (unsigned short)(u >> 16);
}
__device__ __forceinline__ float4 upk4(uint2 v) {
    float4 r;
    r.x = bflo(v.x); r.y = bfhi(v.x);
    r.z = bflo(v.y); r.w = bfhi(v.y);
    return r;
}

// ============================================================================
// fp32 -> bf16 conversion (features once; 6 weight matrices once)
// ============================================================================
__global__ void __launch_bounds__(256)
cvt_bf16_kernel(const float* __restrict__ in, unsigned short* __restrict__ outb,
                int n4) {
    int i = blockIdx.x * 256 + threadIdx.x;
    if (i >= n4) return;
    const float4 v = reinterpret_cast<const float4*>(in)[i];
    uint2 p;
    p.x = (unsigned int)f2bf(v.x) | ((unsigned int)f2bf(v.y) << 16);
    p.y = (unsigned int)f2bf(v.z) | ((unsigned int)f2bf(v.w) << 16);
    reinterpret_cast<uint2*>(outb)[i] = p;
}

// ============================================================================
// CSR build (once per call; edge_index shared by all 3 layers)
// ============================================================================
__global__ void __launch_bounds__(256)
deg_count_kernel(const int* __restrict__ dsts, int* __restrict__ degi, int E) {
    int e = blockIdx.x * 256 + threadIdx.x;
    if (e < E) atomicAdd(&degi[dsts[e]], 1);
}

__global__ void __launch_bounds__(1024)
block_sum_kernel(const int* __restrict__ degi, int* __restrict__ bsum, int N) {
    __shared__ int sm[1024];
    int idx = blockIdx.x * 1024 + threadIdx.x;
    sm[threadIdx.x] = (idx < N) ? degi[idx] : 0;
    __syncthreads();
    for (int s = 512; s > 0; s >>= 1) {
        if (threadIdx.x < s) sm[threadIdx.x] += sm[threadIdx.x + s];
        __syncthreads();
    }
    if (threadIdx.x == 0) bsum[blockIdx.x] = sm[0];
}

__global__ void __launch_bounds__(64)
scan_bsum_kernel(int* __restrict__ bsum, int nb) {
    if (threadIdx.x == 0 && blockIdx.x == 0) {
        int run = 0;
        for (int i = 0; i < nb; ++i) { int v = bsum[i]; bsum[i] = run; run += v; }
    }
}

__global__ void __launch_bounds__(1024)
scan_final_kernel(const int* __restrict__ degi, const int* __restrict__ bsum,
                  int* __restrict__ rowptr, int* __restrict__ cursor, int N) {
    __shared__ int sm[1024];
    int idx = blockIdx.x * 1024 + threadIdx.x;
    int v = (idx < N) ? degi[idx] : 0;
    sm[threadIdx.x] = v;
    __syncthreads();
    for (int s = 1; s < 1024; s <<= 1) {
        int t = (threadIdx.x >= s) ? sm[threadIdx.x - s] : 0;
        __syncthreads();
        sm[threadIdx.x] += t;
        __syncthreads();
    }
    int excl = bsum[blockIdx.x] + sm[threadIdx.x] - v;
    if (idx < N) { rowptr[idx] = excl; cursor[idx] = excl; }
    if (idx == N - 1) rowptr[N] = excl + v;
}

// Partitioned fill (R6-verified win): pass p handles dst in [lo,hi) only ->
// active col slice ~800 KB -> L2 write-combines.
__global__ void __launch_bounds__(256)
fill_pass_kernel(const int* __restrict__ srcs, const int* __restrict__ dsts,
                 int* __restrict__ cursor, int* __restrict__ col, int E,
                 int lo, int hi) {
    int e = blockIdx.x * 256 + threadIdx.x;
    if (e < E) {
        int d = dsts[e];
        if (d >= lo && d < hi) {
            int pos = atomicAdd(&cursor[d], 1);
            col[pos] = srcs[e];
        }
    }
}

// ============================================================================
// Gather-mean over bf16 rows (128 B). One wave per node, NO LDS, NO barriers
// (R4-verified: free-running waves beat fused/barriered variants).
// ============================================================================
__global__ void __launch_bounds__(256)
gather_mean_kernel(const unsigned short* __restrict__ xb,
                   const int* __restrict__ rowptr, const int* __restrict__ col,
                   unsigned short* __restrict__ meanb, int N) {
    int w = (blockIdx.x * 256 + threadIdx.x) >> 6;
    if (w >= N) return;
    const int lane = threadIdx.x & 63;
    const int r = lane >> 4;
    const int c = lane & 15;
    const uint2* x2 = reinterpret_cast<const uint2*>(xb);
    uint2* mean2 = reinterpret_cast<uint2*>(meanb);

    int st = rowptr[w], en = rowptr[w + 1];
    int deg = en - st;

    if (deg == 0) {
        if (r == 0) mean2[(size_t)w * 16 + c] = make_uint2(0, 0);
        return;
    }

    int nb = col[st + min(lane, deg - 1)];
    float4 acc = make_float4(0, 0, 0, 0);

#pragma unroll
    for (int k = 0; k < 4; ++k) {            // slots 0..15 (always)
        int i = 4 * k + r;
        int q = __shfl(nb, min(i, deg - 1), 64);
        float4 v = upk4(x2[(size_t)q * 16 + c]);
        float m = (i < deg) ? 1.0f : 0.0f;
        acc.x += v.x * m; acc.y += v.y * m; acc.z += v.z * m; acc.w += v.w * m;
    }
    if (deg > 16) {
#pragma unroll
        for (int k = 4; k < 8; ++k) {
            int i = 4 * k + r;
            int q = __shfl(nb, min(i, deg - 1), 64);
            float4 v = upk4(x2[(size_t)q * 16 + c]);
            float m = (i < deg) ? 1.0f : 0.0f;
            acc.x += v.x * m; acc.y += v.y * m; acc.z += v.z * m; acc.w += v.w * m;
        }
    }
    if (deg > 32) {
#pragma unroll
        for (int k = 8; k < 16; ++k) {
            int i = 4 * k + r;
            int q = __shfl(nb, min(i, deg - 1), 64);
            float4 v = upk4(x2[(size_t)q * 16 + c]);
            float m = (i < deg) ? 1.0f : 0.0f;
            acc.x += v.x * m; acc.y += v.y * m; acc.z += v.z * m; acc.w += v.w * m;
        }
    }
    for (int base = 64; base < deg; base += 64) {
        int cnt = deg - base;
        int nb2 = col[st + base + min(lane, cnt - 1)];
#pragma unroll
        for (int k = 0; k < 16; ++k) {
            int i = 4 * k + r;
            int q = __shfl(nb2, min(i, cnt - 1), 64);
            float4 v = upk4(x2[(size_t)q * 16 + c]);
            float m = (i < cnt) ? 1.0f : 0.0f;
            acc.x += v.x * m; acc.y += v.y * m; acc.z += v.z * m; acc.w += v.w * m;
        }
    }

#pragma unroll
    for (int off = 16; off <= 32; off <<= 1) {
        acc.x += __shfl_xor(acc.x, off, 64);
        acc.y += __shfl_xor(acc.y, off, 64);
        acc.z += __shfl_xor(acc.z, off, 64);
        acc.w += __shfl_xor(acc.w, off, 64);
    }
    float inv = 1.0f / (float)deg;
    if (r == 0) {
        uint2 p;
        p.x = (unsigned int)f2bf(acc.x * inv) | ((unsigned int)f2bf(acc.y * inv) << 16);
        p.y = (unsigned int)f2bf(acc.z * inv) | ((unsigned int)f2bf(acc.w * inv) << 16);
        mean2[(size_t)w * 16 + c] = p;
    }
}

// ============================================================================
// MFMA transform v3: fixes R8/R9's zero-amortization bug. Weights are staged
// into LDS ONCE PER BLOCK (coalesced); each wave pulls its B-fragments from
// LDS once; then grid-strides over MULTIPLE 16-node tiles (grid 768 -> ~2-3
// tiles/wave, 3 blocks/CU, 12 waves/CU). Per tile: 4 coalesced dwordx4
// A-loads + 16 MFMA + norm epilogue + coalesced store via per-wave LDS
// repack (512 B per store instruction).
//   A frag s: A[m=lane&15][k=quad*8+j]; s=0,1 mean halves, s=2,3 x halves
//   B frag [t][s]: W[16t+(lane&15)][k]
//   C/D: col(n)=lane&15, row(m)=quad*4+reg   (verified R8/R9, absmax 2.0)
// ============================================================================
__global__ void __launch_bounds__(256)
transform_mfma_kernel(const unsigned short* __restrict__ xb,
                      const unsigned short* __restrict__ meanb,
                      const unsigned short* __restrict__ Wlb,
                      const float* __restrict__ bl,
                      const unsigned short* __restrict__ Wrb,
                      unsigned short* __restrict__ h_out,
                      const int* __restrict__ batch, float* __restrict__ out,
                      int N, int final_layer) {
    constexpr int WS = 72;                     // 144 B rows: 16B-aligned b128
    constexpr int RS = DFEAT + 4;              // repack stride (68 ushorts)
    __shared__ unsigned short Wsh[2][DFEAT * WS];   // 18432 B
    __shared__ float blsh[DFEAT];                   //   256 B
    __shared__ unsigned short rep[4][16 * RS];      //  8704 B  (27.4 KB total)

    // ---- block-level weight staging (coalesced global reads)
    for (int t = threadIdx.x; t < DFEAT * DFEAT; t += 256) {
        int rr = t >> 6, cc = t & 63;
        Wsh[0][rr * WS + cc] = Wlb[t];
        Wsh[1][rr * WS + cc] = Wrb[t];
    }
    if (threadIdx.x < DFEAT) blsh[threadIdx.x] = bl[threadIdx.x];
    __syncthreads();

    const int wib  = threadIdx.x >> 6;
    const int lane = threadIdx.x & 63;
    const int colx = lane & 15;
    const int quad = lane >> 4;
    unsigned short* rp = rep[wib];

    // ---- per-wave B-fragment pull from LDS (once)
    bf16x8 Bf[4][4];
    float  bias[4];
#pragma unroll
    for (int t = 0; t < 4; ++t) {
        const unsigned short* wl = &Wsh[0][(16 * t + colx) * WS + quad * 8];
        const unsigned short* wr = &Wsh[1][(16 * t + colx) * WS + quad * 8];
        Bf[t][0] = *reinterpret_cast<const bf16x8*>(wl);
        Bf[t][1] = *reinterpret_cast<const bf16x8*>(wl + 32);
        Bf[t][2] = *reinterpret_cast<const bf16x8*>(wr);
        Bf[t][3] = *reinterpret_cast<const bf16x8*>(wr + 32);
        bias[t] = blsh[16 * t + colx];
    }

    const int tiles = (N + 15) >> 4;
    const int nwaves = gridDim.x * 4;
    int wid = (blockIdx.x * 256 + threadIdx.x) >> 6;

    for (int tile = wid; tile < tiles; tile += nwaves) {
        int m = tile * 16 + colx;
        int mc = min(m, N - 1);
        const unsigned short* mrow = meanb + (size_t)mc * 64 + quad * 8;
        const unsigned short* xrow = xb    + (size_t)mc * 64 + quad * 8;
        bf16x8 A0 = *reinterpret_cast<const bf16x8*>(mrow);
        bf16x8 A1 = *reinterpret_cast<const bf16x8*>(mrow + 32);
        bf16x8 A2 = *reinterpret_cast<const bf16x8*>(xrow);
        bf16x8 A3 = *reinterpret_cast<const bf16x8*>(xrow + 32);

        f32x4 acc[4];
#pragma unroll
        for (int t = 0; t < 4; ++t) {
            f32x4 a = {0.0f, 0.0f, 0.0f, 0.0f};
            a = __builtin_amdgcn_mfma_f32_16x16x32_bf16(A0, Bf[t][0], a, 0, 0, 0);
            a = __builtin_amdgcn_mfma_f32_16x16x32_bf16(A1, Bf[t][1], a, 0, 0, 0);
            a = __builtin_amdgcn_mfma_f32_16x16x32_bf16(A2, Bf[t][2], a, 0, 0, 0);
            a = __builtin_amdgcn_mfma_f32_16x16x32_bf16(A3, Bf[t][3], a, 0, 0, 0);
            acc[t] = a;
        }

        // epilogue: +bias, per-node L2 norm (node m = tile*16 + quad*4 + r)
#pragma unroll
        for (int r = 0; r < 4; ++r) {
            float o0 = acc[0][r] + bias[0];
            float o1 = acc[1][r] + bias[1];
            float o2 = acc[2][r] + bias[2];
            float o3 = acc[3][r] + bias[3];
            float ss = o0 * o0 + o1 * o1 + o2 * o2 + o3 * o3;
            ss += __shfl_xor(ss, 1, 64);   // reduce over colx bits = same node
            ss += __shfl_xor(ss, 2, 64);
            ss += __shfl_xor(ss, 4, 64);
            ss += __shfl_xor(ss, 8, 64);
            float inv = 1.0f / fmaxf(sqrtf(ss), 1e-12f);
            o0 = fmaxf(o0 * inv, 0.0f);
            o1 = fmaxf(o1 * inv, 0.0f);
            o2 = fmaxf(o2 * inv, 0.0f);
            o3 = fmaxf(o3 * inv, 0.0f);

            int nl = quad * 4 + r;           // local node 0..15
            if (final_layer) {
                int node = tile * 16 + nl;
                if (node < N) {
                    float* orow = out + (size_t)batch[node] * DFEAT + colx;
                    atomicAdd(orow,      o0);
                    atomicAdd(orow + 16, o1);
                    atomicAdd(orow + 32, o2);
                    atomicAdd(orow + 48, o3);
                }
            } else {
                unsigned short* rrow = rp + nl * RS;
                rrow[colx]      = f2bf(o0);
                rrow[colx + 16] = f2bf(o1);
                rrow[colx + 32] = f2bf(o2);
                rrow[colx + 48] = f2bf(o3);
            }
        }

        if (!final_layer) {
            // same-wave LDS readback (lgkmcnt ordered) -> coalesced row stores
            // (4 consecutive 128 B rows = 512 B per store instruction)
#pragma unroll
            for (int i = 0; i < 4; ++i) {
                int nl2 = 4 * i + quad;
                int node = tile * 16 + nl2;
                if (node < N) {
                    uint2 v = *reinterpret_cast<const uint2*>(&rp[nl2 * RS + colx * 4]);
                    *reinterpret_cast<uint2*>(h_out + (size_t)node * 64 + colx * 4) = v;
                }
            }
        }
    }
}

// ============================================================================
extern "C" void kernel_launch(void* const* d_in, const int* in_sizes, int n_in,
                              void* d_out, int out_size, void* d_ws, size_t ws_size,
                              hipStream_t stream) {
    const float* x_raw = (const float*)d_in[0];
    const int*   eidx  = (const int*)d_in[1];
    const int*   batch = (const int*)d_in[2];
    const float* Wl0 = (const float*)d_in[3];
    const float* bl0 = (const float*)d_in[4];
    const float* Wr0 = (const float*)d_in[5];
    const float* Wl1 = (const float*)d_in[6];
    const float* bl1 = (const float*)d_in[7];
    const float* Wr1 = (const float*)d_in[8];
    const float* Wl2 = (const float*)d_in[9];
    const float* bl2 = (const float*)d_in[10];
    const float* Wr2 = (const float*)d_in[11];

    const int N = in_sizes[0] / DFEAT;
    const int E = in_sizes[1] / 2;
    const int* srcs = eidx;
    const int* dsts = eidx + E;
    float* out = (float*)d_out;

    const int nb = (N + 1023) / 1024;

    char* ws = (char*)d_ws;
    auto align512 = [](size_t v) { return (v + 511) & ~(size_t)511; };
    size_t off = 0;
    int* degi   = (int*)(ws + off); off += align512((size_t)N * 4);
    int* rowptr = (int*)(ws + off); off += align512(((size_t)N + 1) * 4);
    int* cursor = (int*)(ws + off); off += align512((size_t)N * 4);
    int* bsum   = (int*)(ws + off); off += align512((size_t)nb * 4);
    int* col    = (int*)(ws + off); off += align512((size_t)E * 4);
    unsigned short* xb    = (unsigned short*)(ws + off); off += align512((size_t)N * DFEAT * 2);
    unsigned short* meanb = (unsigned short*)(ws + off); off += align512((size_t)N * DFEAT * 2);
    unsigned short* hA    = (unsigned short*)(ws + off); off += align512((size_t)N * DFEAT * 2);
    unsigned short* hB    = (unsigned short*)(ws + off); off += align512((size_t)N * DFEAT * 2);
    unsigned short* wb[6];
    for (int i = 0; i < 6; ++i) {
        wb[i] = (unsigned short*)(ws + off);
        off += align512((size_t)DFEAT * DFEAT * 2);
    }

    hipMemsetAsync(degi, 0, (size_t)N * 4, stream);
    hipMemsetAsync(out, 0, (size_t)out_size * 4, stream);

    // bf16 conversions: features + 6 weight matrices
    const int n4 = N * DFEAT / 4;
    cvt_bf16_kernel<<<(n4 + 255) / 256, 256, 0, stream>>>(x_raw, xb, n4);
    const int w4 = DFEAT * DFEAT / 4;
    const float* wsrc[6] = {Wl0, Wr0, Wl1, Wr1, Wl2, Wr2};
    for (int i = 0; i < 6; ++i)
        cvt_bf16_kernel<<<(w4 + 255) / 256, 256, 0, stream>>>(wsrc[i], wb[i], w4);

    // CSR build
    deg_count_kernel<<<(E + 255) / 256, 256, 0, stream>>>(dsts, degi, E);
    block_sum_kernel<<<nb, 1024, 0, stream>>>(degi, bsum, N);
    scan_bsum_kernel<<<1, 64, 0, stream>>>(bsum, nb);
    scan_final_kernel<<<nb, 1024, 0, stream>>>(degi, bsum, rowptr, cursor, N);
    const int NPASS = 8;
    const int rng = (N + NPASS - 1) / NPASS;
    for (int p = 0; p < NPASS; ++p) {
        int lo = p * rng;
        int hi = min(N, lo + rng);
        fill_pass_kernel<<<(E + 255) / 256, 256, 0, stream>>>(srcs, dsts, cursor,
                                                              col, E, lo, hi);
    }

    const int gatherBlocks = (N + 3) / 4;   // one wave per node
    const int xfBlocks     = 768;           // 3 blocks/CU, ~2-3 tiles per wave

    // ---- layer 0
    gather_mean_kernel<<<gatherBlocks, 256, 0, stream>>>(xb, rowptr, col, meanb, N);
    transform_mfma_kernel<<<xfBlocks, 256, 0, stream>>>(xb, meanb, wb[0], bl0, wb[1],
                                                        hA, nullptr, nullptr, N, 0);
    // ---- layer 1
    gather_mean_kernel<<<gatherBlocks, 256, 0, stream>>>(hA, rowptr, col, meanb, N);
    transform_mfma_kernel<<<xfBlocks, 256, 0, stream>>>(hA, meanb, wb[2], bl1, wb[3],
                                                        hB, nullptr, nullptr, N, 0);
    // ---- layer 2
    gather_mean_kernel<<<gatherBlocks, 256, 0, stream>>>(hB, rowptr, col, meanb, N);
    transform_mfma_kernel<<<xfBlocks, 256, 0, stream>>>(hB, meanb, wb[4], bl2, wb[5],
                                                        nullptr, batch, out, N, 1);
}